// Round 1
// baseline (416.840 us; speedup 1.0000x reference)
//
#include <hip/hip_runtime.h>
#include <hip/hip_bf16.h>

#define Bn 128
#define Ln 512
#define Hn 512
#define Tn 24
#define START_TAG 22
#define STOP_TAG 23

// ---------------- Kernel 1: emission scores -------------------------------
// emit[b,l,t] = dot(features[b,l,:], W[t,:]) + bias[t]
// One thread per (b,l). W accesses are wave-uniform -> scalar loads (s_load),
// features row streamed as float4 (lines reused across 8 consecutive iters).
__global__ __launch_bounds__(128) void emit_kernel(
    const float* __restrict__ feat, const float* __restrict__ W,
    const float* __restrict__ bias, float* __restrict__ emit) {
  int idx = blockIdx.x * blockDim.x + threadIdx.x;  // = b*Ln + l
  const float* frow = feat + (size_t)idx * Hn;

  float acc[Tn];
#pragma unroll
  for (int t = 0; t < Tn; ++t) acc[t] = bias[t];

  for (int h = 0; h < Hn; h += 4) {
    float4 f = *(const float4*)(frow + h);
#pragma unroll
    for (int t = 0; t < Tn; ++t) {
      float4 w4 = *(const float4*)(W + t * Hn + h);  // uniform address
      acc[t] = fmaf(f.x, w4.x, acc[t]);
      acc[t] = fmaf(f.y, w4.y, acc[t]);
      acc[t] = fmaf(f.z, w4.z, acc[t]);
      acc[t] = fmaf(f.w, w4.w, acc[t]);
    }
  }

  float4* out4 = (float4*)(emit + (size_t)idx * Tn);
#pragma unroll
  for (int q = 0; q < Tn / 4; ++q) {
    float4 v;
    v.x = acc[q * 4 + 0];
    v.y = acc[q * 4 + 1];
    v.z = acc[q * 4 + 2];
    v.w = acc[q * 4 + 3];
    out4[q] = v;
  }
}

// ---------------- Kernel 2: sequential CRF forward recursion --------------
// One wave (64 lanes) per batch element; lane j (j<24) owns tag j.
// new_j = e_j + r + log( sum_k exp(trans[j,k]) * exp(fv_k - r) ),  r = fv[0]
__device__ __forceinline__ float bcast_lane(float v, int lane) {
  return __int_as_float(__builtin_amdgcn_readlane(__float_as_int(v), lane));
}

__global__ __launch_bounds__(64) void crf_kernel(
    const float* __restrict__ emit, const float* __restrict__ trans,
    const int* __restrict__ lengths, float* __restrict__ out) {
  const int b = blockIdx.x;
  const int j = threadIdx.x;  // 0..63, tags are 0..23
  const bool act = (j < Tn);
  const float* eb = emit + (size_t)b * Ln * Tn;
  const int len = lengths[b];

  // Precompute E[j][k] = exp(trans[j,k]) in registers (row START -> all 0).
  float E[Tn];
#pragma unroll
  for (int k = 0; k < Tn; ++k) E[k] = act ? __expf(trans[j * Tn + k]) : 0.0f;

  const float tstop = act ? trans[STOP_TAG * Tn + j] : 0.0f;

  // Step t=0 analytically: fv_j = e0_j + trans[j, START]  (exact in f32)
  float e0 = act ? eb[j] : 0.0f;
  float tjs = act ? trans[j * Tn + START_TAG] : 0.0f;
  float fv = act ? (e0 + tjs) : -1e30f;

  float ecur = (act && len > 1) ? eb[Tn + j] : 0.0f;

  for (int t = 1; t < len; ++t) {
    // prefetch next step's emission (loop-carried, hides latency)
    float enext = (act && (t + 1) < len) ? eb[(t + 1) * Tn + j] : 0.0f;

    float r = __int_as_float(__builtin_amdgcn_readfirstlane(__float_as_int(fv)));
    float w = __expf(fv - r);  // pad lanes: exp(-1e30) = 0, safe

    float s0 = 0.f, s1 = 0.f, s2 = 0.f, s3 = 0.f;
#pragma unroll
    for (int k = 0; k < Tn; k += 4) {
      s0 = fmaf(E[k + 0], bcast_lane(w, k + 0), s0);
      s1 = fmaf(E[k + 1], bcast_lane(w, k + 1), s1);
      s2 = fmaf(E[k + 2], bcast_lane(w, k + 2), s2);
      s3 = fmaf(E[k + 3], bcast_lane(w, k + 3), s3);
    }
    float sum = fmaxf((s0 + s1) + (s2 + s3), 1e-37f);

    float nf = ecur + r + __logf(sum);
    fv = act ? nf : -1e30f;
    ecur = enext;
  }

  // Terminal: logsumexp_j( fv_j + trans[STOP, j] )
  float term = act ? (fv + tstop) : -1e30f;
  float m = term;
#pragma unroll
  for (int d = 16; d >= 1; d >>= 1) m = fmaxf(m, __shfl_xor(m, d, 32));
  float sx = __expf(term - m);
#pragma unroll
  for (int d = 16; d >= 1; d >>= 1) sx += __shfl_xor(sx, d, 32);
  if (j == 0) out[b] = m + __logf(sx);
}

// ---------------- launch ---------------------------------------------------
extern "C" void kernel_launch(void* const* d_in, const int* in_sizes, int n_in,
                              void* d_out, int out_size, void* d_ws,
                              size_t ws_size, hipStream_t stream) {
  const float* feat = (const float*)d_in[0];   // [B, L, H]
  const float* W = (const float*)d_in[1];      // [T, H]
  const float* bias = (const float*)d_in[2];   // [T]
  const float* trans = (const float*)d_in[3];  // [T, T]
  const int* lengths = (const int*)d_in[4];    // [B]
  float* out = (float*)d_out;                  // [B]
  float* emit = (float*)d_ws;                  // [B, L, T] scratch (6.3 MB)

  emit_kernel<<<(Bn * Ln) / 128, 128, 0, stream>>>(feat, W, bias, emit);
  crf_kernel<<<Bn, 64, 0, stream>>>(emit, trans, lengths, out);
}

// Round 2
// 366.246 us; speedup vs baseline: 1.1381x; 1.1381x over previous
//
#include <hip/hip_runtime.h>
#include <hip/hip_bf16.h>

#define Bn 128
#define Ln 512
#define Hn 512
#define Tn 24
#define START_TAG 22
#define STOP_TAG 23

// ---------------- Kernel 1: EXP'd emission scores -------------------------
// eemit[b,l,t] = exp( dot(features[b,l,:], W[t,:]) + bias[t] )
// One wave handles 8 rows: lane = (g,s), g=row-group (0..7), s=h-segment (0..7).
// Lane accumulates all 24 tags over h in {i*32 + s*4 .. +3}, i=0..15.
// Feature loads: 8 groups x 128 contiguous B = fully coalesced 1 KB/instr.
// W loads: same address across the 8 groups -> 8-way dedup, L2-served.
__global__ __launch_bounds__(256) void emit_kernel(
    const float* __restrict__ feat, const float* __restrict__ W,
    const float* __restrict__ bias, float* __restrict__ eemit) {
  const int tid = blockIdx.x * 256 + threadIdx.x;
  const int wave = tid >> 6;
  const int lane = threadIdx.x & 63;
  const int g = lane >> 3;  // row within wave's 8-row tile
  const int s = lane & 7;   // h-segment
  const int row = wave * 8 + g;
  const float* frow = feat + (size_t)row * Hn + s * 4;
  const float* wbase = W + s * 4;

  float acc[Tn];
#pragma unroll
  for (int t = 0; t < Tn; ++t) acc[t] = 0.0f;

#pragma unroll 2
  for (int i = 0; i < 16; ++i) {
    float4 f = *(const float4*)(frow + i * 32);
#pragma unroll
    for (int t = 0; t < Tn; ++t) {
      float4 w4 = *(const float4*)(wbase + t * Hn + i * 32);
      acc[t] = fmaf(f.x, w4.x, acc[t]);
      acc[t] = fmaf(f.y, w4.y, acc[t]);
      acc[t] = fmaf(f.z, w4.z, acc[t]);
      acc[t] = fmaf(f.w, w4.w, acc[t]);
    }
  }

  // reduce partial dots across the 8 h-segments (lane bits 0..2)
#pragma unroll
  for (int t = 0; t < Tn; ++t) {
    float v = acc[t];
    v += __shfl_xor(v, 1, 64);
    v += __shfl_xor(v, 2, 64);
    v += __shfl_xor(v, 4, 64);
    acc[t] = v + bias[t];
  }

  if (s == 0) {
    float4* dst = (float4*)(eemit + (size_t)row * Tn);
#pragma unroll
    for (int q = 0; q < 6; ++q) {
      float4 v;
      v.x = __expf(acc[q * 4 + 0]);
      v.y = __expf(acc[q * 4 + 1]);
      v.z = __expf(acc[q * 4 + 2]);
      v.w = __expf(acc[q * 4 + 3]);
      dst[q] = v;
    }
  }
}

// ---------------- Kernel 2: CRF forward recursion (exp domain) ------------
// One wave per batch element; lane j<24 owns tag j, tracking u_j = exp(fv_j - R).
// Step: u'_j = ee_j * sum_k E[j][k] * u_k   (E = exp(trans), in registers)
// Renormalize by power-of-2 of the wave max every 8 steps (exact scaling).
#define RL(k) __int_as_float(__builtin_amdgcn_readlane(__float_as_int(u), (k)))

#define STEP(EE)                                              \
  do {                                                        \
    float s0 = E[0] * RL(0);                                  \
    float s1 = E[1] * RL(1);                                  \
    float s2 = E[2] * RL(2);                                  \
    float s3 = E[3] * RL(3);                                  \
    s0 = fmaf(E[4], RL(4), s0);                               \
    s1 = fmaf(E[5], RL(5), s1);                               \
    s2 = fmaf(E[6], RL(6), s2);                               \
    s3 = fmaf(E[7], RL(7), s3);                               \
    s0 = fmaf(E[8], RL(8), s0);                               \
    s1 = fmaf(E[9], RL(9), s1);                               \
    s2 = fmaf(E[10], RL(10), s2);                             \
    s3 = fmaf(E[11], RL(11), s3);                             \
    s0 = fmaf(E[12], RL(12), s0);                             \
    s1 = fmaf(E[13], RL(13), s1);                             \
    s2 = fmaf(E[14], RL(14), s2);                             \
    s3 = fmaf(E[15], RL(15), s3);                             \
    s0 = fmaf(E[16], RL(16), s0);                             \
    s1 = fmaf(E[17], RL(17), s1);                             \
    s2 = fmaf(E[18], RL(18), s2);                             \
    s3 = fmaf(E[19], RL(19), s3);                             \
    s0 = fmaf(E[20], RL(20), s0);                             \
    s1 = fmaf(E[21], RL(21), s1);                             \
    s2 = fmaf(E[22], RL(22), s2);                             \
    s3 = fmaf(E[23], RL(23), s3);                             \
    u = (EE) * ((s0 + s1) + (s2 + s3));                       \
  } while (0)

#define RENORM()                                              \
  do {                                                        \
    float m = u;                                              \
    m = fmaxf(m, __shfl_xor(m, 1, 64));                       \
    m = fmaxf(m, __shfl_xor(m, 2, 64));                       \
    m = fmaxf(m, __shfl_xor(m, 4, 64));                       \
    m = fmaxf(m, __shfl_xor(m, 8, 64));                       \
    m = fmaxf(m, __shfl_xor(m, 16, 64));                      \
    m = fmaxf(m, __shfl_xor(m, 32, 64));                      \
    int eb = ((__float_as_int(m) >> 23) & 255) - 127;         \
    float scale = __int_as_float((127 - eb) << 23);           \
    u *= scale;                                               \
    R += (float)eb * 0.693147180559945f;                      \
  } while (0)

__global__ __launch_bounds__(64) void crf_kernel(
    const float* __restrict__ eemit, const float* __restrict__ trans,
    const int* __restrict__ lengths, float* __restrict__ out) {
  __shared__ __align__(16) float lds[12448];  // 516*24 + 64 pad
  const int b = blockIdx.x;
  const int j = threadIdx.x;  // 0..63, tags 0..23
  const bool act = (j < Tn);
  const int len = lengths[b];

  // ---- stage this sequence's exp'd emissions into LDS (batched float4) ----
  const float4* src4 = (const float4*)(eemit + (size_t)b * Ln * Tn);
  float4* lds4 = (float4*)lds;
  int n4s = len * 6 + 24;  // 6 float4 per timestep + 4-row prefetch pad
  if (n4s > 3072) n4s = 3072;
  for (int base4 = 0; base4 < 3072; base4 += 512) {
    if (base4 >= n4s) break;
    float4 tmp[8];
#pragma unroll
    for (int q = 0; q < 8; ++q) tmp[q] = src4[base4 + q * 64 + j];
#pragma unroll
    for (int q = 0; q < 8; ++q) lds4[base4 + q * 64 + j] = tmp[q];
  }
  __syncthreads();

  // ---- constants in registers ----
  float E[Tn];
#pragma unroll
  for (int k = 0; k < Tn; ++k)
    E[k] = act ? __expf(trans[j * Tn + k]) : 0.0f;
  const float ets = act ? __expf(trans[STOP_TAG * Tn + j]) : 0.0f;

  // ---- init (t = 0): u_j = exp(e0_j) * exp(trans[j, START]) ----
  float R = 0.0f;
  float tjs = act ? trans[j * Tn + START_TAG] : -1e30f;
  float u = act ? lds[j] * __expf(tjs) : 0.0f;
  RENORM();

#define L(T) lds[(T) * Tn + j]

  int t = 1;
  float c0, c1, c2, c3;
  if (t + 4 <= len) { c0 = L(t); c1 = L(t + 1); c2 = L(t + 2); c3 = L(t + 3); }
  while (t + 8 <= len) {
    float n0 = L(t + 4), n1 = L(t + 5), n2 = L(t + 6), n3 = L(t + 7);
    STEP(c0); STEP(c1); STEP(c2); STEP(c3);
    c0 = L(t + 8); c1 = L(t + 9); c2 = L(t + 10); c3 = L(t + 11);
    STEP(n0); STEP(n1); STEP(n2); STEP(n3);
    RENORM();
    t += 8;
  }
  if (t + 4 <= len) {  // 4..7 steps remain; c0..c3 hold L(t..t+3)
    STEP(c0); STEP(c1); STEP(c2); STEP(c3);
    t += 4;
  }
  for (; t < len; ++t) {
    float ee = L(t);
    STEP(ee);
  }

  // ---- terminal: out = R + log( sum_j u_j * exp(trans[STOP, j]) ) ----
  float term = u * ets;
  term += __shfl_xor(term, 1, 64);
  term += __shfl_xor(term, 2, 64);
  term += __shfl_xor(term, 4, 64);
  term += __shfl_xor(term, 8, 64);
  term += __shfl_xor(term, 16, 64);
  term += __shfl_xor(term, 32, 64);
  if (j == 0) out[b] = R + logf(term);
}

// ---------------- launch ---------------------------------------------------
extern "C" void kernel_launch(void* const* d_in, const int* in_sizes, int n_in,
                              void* d_out, int out_size, void* d_ws,
                              size_t ws_size, hipStream_t stream) {
  const float* feat = (const float*)d_in[0];   // [B, L, H]
  const float* W = (const float*)d_in[1];      // [T, H]
  const float* bias = (const float*)d_in[2];   // [T]
  const float* trans = (const float*)d_in[3];  // [T, T]
  const int* lengths = (const int*)d_in[4];    // [B]
  float* out = (float*)d_out;                  // [B]
  float* eemit = (float*)d_ws;                 // [B, L, T] exp'd emissions

  emit_kernel<<<(Bn * Ln) / (8 * 4), 256, 0, stream>>>(feat, W, bias, eemit);
  crf_kernel<<<Bn, 64, 0, stream>>>(eemit, trans, lengths, out);
}

// Round 3
// 276.751 us; speedup vs baseline: 1.5062x; 1.3234x over previous
//
#include <hip/hip_runtime.h>
#include <hip/hip_bf16.h>

#define Bn 128
#define Ln 512
#define Hn 512
#define Tn 24
#define START_TAG 22
#define STOP_TAG 23

// ================= Kernel 1: emission GEMM via MFMA (bf16) ================
// eemit[row, t] = exp( dot(feat[row,:], W[t,:]) + bias[t] ),  row = b*L + l
// Block: 256 thr = 4 waves, 64 rows/block. Wave: 16 rows, K-loop 16x K=32.
// mfma_f32_16x16x32_bf16; A lane layout: row = lane&15, k = (lane>>4)*8 + i;
// B: col = lane&15, k = (lane>>4)*8 + i; C/D: col = lane&15, row=(lane>>4)*4+r.
using frag_ab = __attribute__((ext_vector_type(8))) short;
using frag_cd = __attribute__((ext_vector_type(4))) float;

__device__ __forceinline__ unsigned short f2bf(float x) {  // RNE f32->bf16
  unsigned u = __float_as_uint(x);
  return (unsigned short)((u + 0x7FFFu + ((u >> 16) & 1u)) >> 16);
}

__global__ __launch_bounds__(256) void emit_kernel(
    const float* __restrict__ feat, const float* __restrict__ W,
    const float* __restrict__ bias, float* __restrict__ eemit) {
  __shared__ __align__(16) short Wl[Tn][520];  // bf16 bits, row pad: 1040 B
  for (int idx = threadIdx.x; idx < Tn * Hn; idx += 256) {
    int t = idx >> 9, h = idx & 511;
    Wl[t][h] = (short)f2bf(W[idx]);
  }
  __syncthreads();

  const int wv = threadIdx.x >> 6, ln = threadIdx.x & 63;
  const int m = ln & 15, g = ln >> 4;
  const int row0 = blockIdx.x * 64 + wv * 16;
  const float* fp = feat + (size_t)(row0 + m) * Hn + g * 8;
  const short* w0 = &Wl[m][g * 8];             // tags 0..15
  const short* w1 = &Wl[16 + (m & 7)][g * 8];  // tags 16..23 (dup for n>=8)

  frag_cd acc0 = {0.f, 0.f, 0.f, 0.f}, acc1 = {0.f, 0.f, 0.f, 0.f};
#pragma unroll 4
  for (int kk = 0; kk < 16; ++kk) {
    float4 fa = *(const float4*)(fp + kk * 32);
    float4 fb = *(const float4*)(fp + kk * 32 + 4);
    frag_ab a;
    a[0] = (short)f2bf(fa.x); a[1] = (short)f2bf(fa.y);
    a[2] = (short)f2bf(fa.z); a[3] = (short)f2bf(fa.w);
    a[4] = (short)f2bf(fb.x); a[5] = (short)f2bf(fb.y);
    a[6] = (short)f2bf(fb.z); a[7] = (short)f2bf(fb.w);
    frag_ab b0 = *(const frag_ab*)(w0 + kk * 32);
    frag_ab b1 = *(const frag_ab*)(w1 + kk * 32);
    acc0 = __builtin_amdgcn_mfma_f32_16x16x32_bf16(a, b0, acc0, 0, 0, 0);
    acc1 = __builtin_amdgcn_mfma_f32_16x16x32_bf16(a, b1, acc1, 0, 0, 0);
  }

  const int n = ln & 15;
  const int crow = row0 + (ln >> 4) * 4;
  float b0v = bias[n];
#pragma unroll
  for (int r = 0; r < 4; ++r)
    eemit[(size_t)(crow + r) * Tn + n] = __expf(acc0[r] + b0v);
  if (n < 8) {
    float b1v = bias[16 + n];
#pragma unroll
    for (int r = 0; r < 4; ++r)
      eemit[(size_t)(crow + r) * Tn + 16 + n] = __expf(acc1[r] + b1v);
  }
}

// ================= Kernel 2: CRF recursion, exp domain ====================
// 16 blocks x 512 thr = 8 waves/block (2 waves/SIMD), 1 chain per wave.
// Lane j<24 owns tag j:  u'_j = ee_j * sum_k E[j][k] * u_k,  E = exp(trans).
// All 24 readlanes issued FIRST (distinct SGPRs) to kill the per-pair
// VALU->SGPR hazard; renorm = power-of-2 rescale by lane0's exponent.
__device__ __forceinline__ float rlf(float v, int l) {
  return __int_as_float(__builtin_amdgcn_readlane(__float_as_int(v), l));
}

#define STEP(EE)                                                          \
  do {                                                                    \
    float r0 = rlf(u, 0), r1 = rlf(u, 1), r2 = rlf(u, 2), r3 = rlf(u, 3), \
          r4 = rlf(u, 4), r5 = rlf(u, 5), r6 = rlf(u, 6), r7 = rlf(u, 7), \
          r8 = rlf(u, 8), r9 = rlf(u, 9), r10 = rlf(u, 10),               \
          r11 = rlf(u, 11), r12 = rlf(u, 12), r13 = rlf(u, 13),           \
          r14 = rlf(u, 14), r15 = rlf(u, 15), r16 = rlf(u, 16),           \
          r17 = rlf(u, 17), r18 = rlf(u, 18), r19 = rlf(u, 19),           \
          r20 = rlf(u, 20), r21 = rlf(u, 21), r22 = rlf(u, 22),           \
          r23 = rlf(u, 23);                                               \
    float s0 = E[0] * r0, s1 = E[1] * r1, s2 = E[2] * r2, s3 = E[3] * r3; \
    s0 = fmaf(E[4], r4, s0);   s1 = fmaf(E[5], r5, s1);                   \
    s2 = fmaf(E[6], r6, s2);   s3 = fmaf(E[7], r7, s3);                   \
    s0 = fmaf(E[8], r8, s0);   s1 = fmaf(E[9], r9, s1);                   \
    s2 = fmaf(E[10], r10, s2); s3 = fmaf(E[11], r11, s3);                 \
    s0 = fmaf(E[12], r12, s0); s1 = fmaf(E[13], r13, s1);                 \
    s2 = fmaf(E[14], r14, s2); s3 = fmaf(E[15], r15, s3);                 \
    s0 = fmaf(E[16], r16, s0); s1 = fmaf(E[17], r17, s1);                 \
    s2 = fmaf(E[18], r18, s2); s3 = fmaf(E[19], r19, s3);                 \
    s0 = fmaf(E[20], r20, s0); s1 = fmaf(E[21], r21, s1);                 \
    s2 = fmaf(E[22], r22, s2); s3 = fmaf(E[23], r23, s3);                 \
    u = (EE) * ((s0 + s1) + (s2 + s3));                                   \
  } while (0)

#define RENORM()                                                          \
  do {                                                                    \
    float m0 =                                                            \
        __int_as_float(__builtin_amdgcn_readfirstlane(__float_as_int(u)));\
    int eb = ((__float_as_int(m0) >> 23) & 255) - 127;                    \
    u *= __int_as_float((127 - eb) << 23);                                \
    R += (float)eb * 0.693147180559945f;                                  \
  } while (0)

#define LDE(DST, TT)                          \
  do {                                        \
    int _tc = (TT);                           \
    if (_tc > Ln - 1) _tc = Ln - 1;           \
    DST = ep[(size_t)_tc * Tn];               \
  } while (0)

__global__ __launch_bounds__(512) void crf_kernel(
    const float* __restrict__ eemit, const float* __restrict__ trans,
    const int* __restrict__ lengths, float* __restrict__ out) {
  const int w = threadIdx.x >> 6;
  const int j = threadIdx.x & 63;
  const int b = blockIdx.x * 8 + w;
  const bool act = (j < Tn);
  const int jj = act ? j : 0;  // clamped index for trans reads
  const int len = lengths[b];
  const float* ep = eemit + (size_t)b * (Ln * Tn) + (act ? j : Tn - 1);

  float E[Tn];
#pragma unroll
  for (int k = 0; k < Tn; ++k) {
    float tv = trans[jj * Tn + k];
    E[k] = act ? __expf(tv) : 0.0f;
  }
  const float ets = act ? __expf(trans[STOP_TAG * Tn + j]) : 0.0f;

  // t = 0 exact: u_j = ee(0)_j * exp(trans[j, START])
  float R = 0.0f;
  float u = act ? ep[0] * __expf(trans[jj * Tn + START_TAG]) : 0.0f;
  RENORM();

  float p0, p1, p2, p3, p4, p5, p6, p7;
  float q0, q1, q2, q3, q4, q5, q6, q7;
  int t = 1;
  LDE(p0, t + 0); LDE(p1, t + 1); LDE(p2, t + 2); LDE(p3, t + 3);
  LDE(p4, t + 4); LDE(p5, t + 5); LDE(p6, t + 6); LDE(p7, t + 7);

  while (t + 16 <= len) {
    LDE(q0, t + 8);  LDE(q1, t + 9);  LDE(q2, t + 10); LDE(q3, t + 11);
    LDE(q4, t + 12); LDE(q5, t + 13); LDE(q6, t + 14); LDE(q7, t + 15);
    STEP(p0); STEP(p1); STEP(p2); STEP(p3);
    STEP(p4); STEP(p5); STEP(p6); STEP(p7);
    RENORM();
    LDE(p0, t + 16); LDE(p1, t + 17); LDE(p2, t + 18); LDE(p3, t + 19);
    LDE(p4, t + 20); LDE(p5, t + 21); LDE(p6, t + 22); LDE(p7, t + 23);
    STEP(q0); STEP(q1); STEP(q2); STEP(q3);
    STEP(q4); STEP(q5); STEP(q6); STEP(q7);
    RENORM();
    t += 16;
  }
  if (t + 8 <= len) {
    LDE(q0, t + 8);  LDE(q1, t + 9);  LDE(q2, t + 10); LDE(q3, t + 11);
    LDE(q4, t + 12); LDE(q5, t + 13); LDE(q6, t + 14); LDE(q7, t + 15);
    STEP(p0); STEP(p1); STEP(p2); STEP(p3);
    STEP(p4); STEP(p5); STEP(p6); STEP(p7);
    RENORM();
    p0 = q0; p1 = q1; p2 = q2; p3 = q3;
    p4 = q4; p5 = q5; p6 = q6; p7 = q7;
    t += 8;
  }
  // tail: 0..7 remaining steps
  if (t + 0 < len) { STEP(p0);
  if (t + 1 < len) { STEP(p1);
  if (t + 2 < len) { STEP(p2);
  if (t + 3 < len) { STEP(p3);
  if (t + 4 < len) { STEP(p4);
  if (t + 5 < len) { STEP(p5);
  if (t + 6 < len) { STEP(p6); } } } } } } }

  // terminal: out[b] = R + log( sum_j u_j * exp(trans[STOP, j]) )
  float term = u * ets;
  term += __shfl_xor(term, 1, 64);
  term += __shfl_xor(term, 2, 64);
  term += __shfl_xor(term, 4, 64);
  term += __shfl_xor(term, 8, 64);
  term += __shfl_xor(term, 16, 64);
  term += __shfl_xor(term, 32, 64);
  if (j == 0) out[b] = R + logf(term);
}

// ================= launch ==================================================
extern "C" void kernel_launch(void* const* d_in, const int* in_sizes, int n_in,
                              void* d_out, int out_size, void* d_ws,
                              size_t ws_size, hipStream_t stream) {
  const float* feat = (const float*)d_in[0];   // [B, L, H]
  const float* W = (const float*)d_in[1];      // [T, H]
  const float* bias = (const float*)d_in[2];   // [T]
  const float* trans = (const float*)d_in[3];  // [T, T]
  const int* lengths = (const int*)d_in[4];    // [B]
  float* out = (float*)d_out;                  // [B]
  float* eemit = (float*)d_ws;                 // [B, L, T] exp'd emissions

  emit_kernel<<<(Bn * Ln) / 64, 256, 0, stream>>>(feat, W, bias, eemit);
  crf_kernel<<<Bn / 8, 512, 0, stream>>>(eemit, trans, lengths, out);
}

// Round 4
// 230.433 us; speedup vs baseline: 1.8089x; 1.2010x over previous
//
#include <hip/hip_runtime.h>
#include <hip/hip_bf16.h>

typedef unsigned int uint;
typedef unsigned short ushort;

#define Bn 128
#define Ln 512
#define Hn 512
#define Tn 24
#define START_TAG 22
#define STOP_TAG 23
#define NCH 8   // chunks per batch
#define CHL 64  // timesteps per chunk

using frag_ab = __attribute__((ext_vector_type(8))) short;
using frag_cd = __attribute__((ext_vector_type(4))) float;
union ABU { frag_ab f; uint u[4]; };

// pack two f32 into one u32 of 2 bf16 (truncation) via v_perm
#define PACKW(x, y) \
  __builtin_amdgcn_perm(__float_as_uint(y), __float_as_uint(x), 0x07060302u)

__device__ __forceinline__ float bf2f(ushort v) {
  return __uint_as_float(((uint)v) << 16);
}
__device__ __forceinline__ ushort f2bf_rne(float x) {
  uint u = __float_as_uint(x);
  return (ushort)((u + 0x7FFFu + ((u >> 16) & 1u)) >> 16);
}
__device__ __forceinline__ float rlf(float v, int l) {
  return __int_as_float(__builtin_amdgcn_readlane(__float_as_int(v), l));
}

// ============ Kernel 0: W f32 -> bf16 (once per launch) ====================
__global__ __launch_bounds__(256) void wconv(const float* __restrict__ W,
                                             ushort* __restrict__ Wbf) {
  int i = blockIdx.x * 256 + threadIdx.x;
  if (i < Tn * Hn) Wbf[i] = f2bf_rne(W[i]);
}

// ============ Kernel 1: emission GEMM via MFMA, exp'd, bf16 out ============
// Wave handles 64 rows (4 M-tiles) x 24 tags (2 N-tiles); B-frags from
// L1-resident bf16 W; A packed from f32 features via v_perm truncation.
__global__ __launch_bounds__(256) void emit_kernel(
    const float* __restrict__ feat, const ushort* __restrict__ Wbf,
    const float* __restrict__ bias, ushort* __restrict__ eemit) {
  const int wv = threadIdx.x >> 6, l = threadIdx.x & 63;
  const int ct = l & 15, g = l >> 4;
  const int row0 = blockIdx.x * 256 + wv * 64;
  const float* f0 = feat + (size_t)(row0 + ct) * Hn + 8 * g;
  const float* f1 = f0 + (size_t)16 * Hn;
  const float* f2 = f0 + (size_t)32 * Hn;
  const float* f3 = f0 + (size_t)48 * Hn;
  const ushort* w0p = Wbf + ct * Hn + 8 * g;
  const ushort* w1p = Wbf + (16 + (ct & 7)) * Hn + 8 * g;

  frag_cd acc[4][2];
#pragma unroll
  for (int q = 0; q < 4; ++q)
#pragma unroll
    for (int n = 0; n < 2; ++n)
#pragma unroll
      for (int r = 0; r < 4; ++r) acc[q][n][r] = 0.f;

#pragma unroll 2
  for (int kk = 0; kk < 16; ++kk) {
    const int off = kk * 32;
    frag_ab bw0 = *(const frag_ab*)(w0p + off);
    frag_ab bw1 = *(const frag_ab*)(w1p + off);
#define EMIT_TILE(Q, FP)                                                     \
    {                                                                        \
      float4 fa = *(const float4*)((FP) + off);                              \
      float4 fb = *(const float4*)((FP) + off + 4);                          \
      ABU A;                                                                 \
      A.u[0] = PACKW(fa.x, fa.y); A.u[1] = PACKW(fa.z, fa.w);                \
      A.u[2] = PACKW(fb.x, fb.y); A.u[3] = PACKW(fb.z, fb.w);                \
      acc[Q][0] = __builtin_amdgcn_mfma_f32_16x16x32_bf16(A.f, bw0,          \
                                                          acc[Q][0], 0,0,0); \
      acc[Q][1] = __builtin_amdgcn_mfma_f32_16x16x32_bf16(A.f, bw1,          \
                                                          acc[Q][1], 0,0,0); \
    }
    EMIT_TILE(0, f0)
    EMIT_TILE(1, f1)
    EMIT_TILE(2, f2)
    EMIT_TILE(3, f3)
#undef EMIT_TILE
  }

  const float bs0 = bias[ct];
  const float bs1 = bias[16 + (ct & 7)];
#pragma unroll
  for (int q = 0; q < 4; ++q) {
    int crow = row0 + q * 16 + 4 * g;
#pragma unroll
    for (int r = 0; r < 4; ++r) {
      eemit[(size_t)(crow + r) * Tn + ct] = f2bf_rne(__expf(acc[q][0][r] + bs0));
      if (ct < 8)
        eemit[(size_t)(crow + r) * Tn + 16 + ct] =
            f2bf_rne(__expf(acc[q][1][r] + bs1));
    }
  }
}

// ============ Kernel 2 (passA): chunk products of M_t = diag(ee_t)*E =======
// One wave per (batch, chunk). P <- M_t * P sequentially via 4x
// mfma_16x16x32_bf16 (32x32 padded). D->B re-layout through ping-pong LDS.
// M_t = I for t >= len (handles variable lengths exactly).
__global__ __launch_bounds__(64) void passA(
    const ushort* __restrict__ eemit, const float* __restrict__ trans,
    const int* __restrict__ lengths, ushort* __restrict__ G,
    float* __restrict__ Rc) {
  __shared__ __align__(16) char lds[2 * 2560];
  const int bid = blockIdx.x;
  const int b = bid >> 3, c = bid & 7;
  const int l = threadIdx.x;
  const int ct = l & 15, g = l >> 4;
  const int ct2 = 16 + (ct & 7);
  const bool c8 = ct < 8;
  const int len = lengths[b];
  int t_lo = c * CHL; if (t_lo < 1) t_lo = 1;
  int t_hi = (c + 1) * CHL; if (t_hi > len) t_hi = len;

  // E rows for this lane's A-frag slots (zero-padded beyond 24)
  float E0[8], E1[8];
#pragma unroll
  for (int i = 0; i < 8; ++i) {
    int k = 8 * g + i;
    int kc = k < 23 ? k : 23;
    float t0 = trans[ct * Tn + kc];
    float t1 = trans[ct2 * Tn + kc];
    E0[i] = (k < Tn) ? __expf(t0) : 0.f;
    E1[i] = (k < Tn && c8) ? __expf(t1) : 0.f;
  }

  // P = I in D-frag form: value(m,n,r) at row 16m+4g+r, col 16n+ct
  frag_cd D[2][2];
#pragma unroll
  for (int m = 0; m < 2; ++m)
#pragma unroll
    for (int n = 0; n < 2; ++n)
#pragma unroll
      for (int r = 0; r < 4; ++r)
        D[m][n][r] = (16 * m + 4 * g + r == 16 * n + ct) ? 1.f : 0.f;

  float R = 0.f;
  const ushort* ebase = eemit + (size_t)b * (Ln * Tn);
  int pp = 0;

#define LDP(A, B, T)                                      \
  do {                                                    \
    int _tc = (T); if (_tc > Ln - 1) _tc = Ln - 1;        \
    const ushort* _p = ebase + _tc * Tn;                  \
    float _a = bf2f(_p[ct]);                              \
    float _b = bf2f(_p[ct2]);                             \
    A = _a; B = c8 ? _b : 0.f;                            \
  } while (0)

// one product step: pack P(=D) -> LDS, read B-frags, build A from ee, MFMA
#define STEPA(EA, EB)                                                         \
  do {                                                                        \
    char* Lp = lds + (pp ? 2560 : 0);                                         \
    uint2 wv_;                                                                \
    wv_.x = PACKW(D[0][0][0], D[0][0][1]);                                    \
    wv_.y = PACKW(D[0][0][2], D[0][0][3]);                                    \
    *(uint2*)(Lp + ct * 80 + 8 * g) = wv_;                                    \
    wv_.x = PACKW(D[0][1][0], D[0][1][1]);                                    \
    wv_.y = PACKW(D[0][1][2], D[0][1][3]);                                    \
    *(uint2*)(Lp + (16 + ct) * 80 + 8 * g) = wv_;                             \
    wv_.x = PACKW(D[1][0][0], D[1][0][1]);                                    \
    wv_.y = PACKW(D[1][0][2], D[1][0][3]);                                    \
    *(uint2*)(Lp + ct * 80 + 32 + 8 * g) = wv_;                               \
    wv_.x = PACKW(D[1][1][0], D[1][1][1]);                                    \
    wv_.y = PACKW(D[1][1][2], D[1][1][3]);                                    \
    *(uint2*)(Lp + (16 + ct) * 80 + 32 + 8 * g) = wv_;                        \
    frag_ab Bf0 = *(frag_ab*)(Lp + ct * 80 + 16 * g);                         \
    frag_ab Bf1 = *(frag_ab*)(Lp + (16 + ct) * 80 + 16 * g);                  \
    ABU A0, A1;                                                               \
    float _ea = (EA), _eb2 = (EB);                                            \
    A0.u[0] = PACKW(_ea * E0[0], _ea * E0[1]);                                \
    A0.u[1] = PACKW(_ea * E0[2], _ea * E0[3]);                                \
    A0.u[2] = PACKW(_ea * E0[4], _ea * E0[5]);                                \
    A0.u[3] = PACKW(_ea * E0[6], _ea * E0[7]);                                \
    A1.u[0] = PACKW(_eb2 * E1[0], _eb2 * E1[1]);                              \
    A1.u[1] = PACKW(_eb2 * E1[2], _eb2 * E1[3]);                              \
    A1.u[2] = PACKW(_eb2 * E1[4], _eb2 * E1[5]);                              \
    A1.u[3] = PACKW(_eb2 * E1[6], _eb2 * E1[7]);                              \
    frag_cd _z = {0.f, 0.f, 0.f, 0.f};                                        \
    D[0][0] = __builtin_amdgcn_mfma_f32_16x16x32_bf16(A0.f, Bf0, _z, 0,0,0);  \
    D[0][1] = __builtin_amdgcn_mfma_f32_16x16x32_bf16(A0.f, Bf1, _z, 0,0,0);  \
    D[1][0] = __builtin_amdgcn_mfma_f32_16x16x32_bf16(A1.f, Bf0, _z, 0,0,0);  \
    D[1][1] = __builtin_amdgcn_mfma_f32_16x16x32_bf16(A1.f, Bf1, _z, 0,0,0);  \
    pp ^= 1;                                                                  \
  } while (0)

#define RENORMA()                                                             \
  do {                                                                        \
    float mx = D[0][0][0];                                                    \
    _Pragma("unroll") for (int m = 0; m < 2; ++m)                             \
      _Pragma("unroll") for (int n = 0; n < 2; ++n)                           \
        _Pragma("unroll") for (int r = 0; r < 4; ++r)                         \
          mx = fmaxf(mx, D[m][n][r]);                                         \
    mx = fmaxf(mx, __shfl_xor(mx, 1, 64));                                    \
    mx = fmaxf(mx, __shfl_xor(mx, 2, 64));                                    \
    mx = fmaxf(mx, __shfl_xor(mx, 4, 64));                                    \
    mx = fmaxf(mx, __shfl_xor(mx, 8, 64));                                    \
    mx = fmaxf(mx, __shfl_xor(mx, 16, 64));                                   \
    mx = fmaxf(mx, __shfl_xor(mx, 32, 64));                                   \
    int eb = ((__float_as_int(mx) >> 23) & 255) - 127;                        \
    float sc = __int_as_float((uint)(127 - eb) << 23);                        \
    _Pragma("unroll") for (int m = 0; m < 2; ++m)                             \
      _Pragma("unroll") for (int n = 0; n < 2; ++n)                           \
        _Pragma("unroll") for (int r = 0; r < 4; ++r)                         \
          D[m][n][r] *= sc;                                                   \
    R += (float)eb * 0.6931471805599453f;                                     \
  } while (0)

  int t = t_lo;
  float a0, a1, a2, a3, e0, e1, e2, e3;
  LDP(a0, e0, t); LDP(a1, e1, t + 1); LDP(a2, e2, t + 2); LDP(a3, e3, t + 3);
  while (t + 4 <= t_hi) {
    float n0, n1, n2, n3, m0, m1, m2, m3;
    LDP(n0, m0, t + 4); LDP(n1, m1, t + 5);
    LDP(n2, m2, t + 6); LDP(n3, m3, t + 7);
    STEPA(a0, e0); STEPA(a1, e1); STEPA(a2, e2); STEPA(a3, e3);
    RENORMA();
    a0 = n0; a1 = n1; a2 = n2; a3 = n3;
    e0 = m0; e1 = m1; e2 = m2; e3 = m3;
    t += 4;
  }
  while (t < t_hi) {
    float xa, xb;
    LDP(xa, xb, t);
    STEPA(xa, xb);
    RENORMA();
    ++t;
  }

  // store chunk product transposed: G[col][row] = P[row][col], bf16
  ushort* Gc = G + (size_t)bid * 1024;
  uint2 w2;
  w2.x = PACKW(D[0][0][0], D[0][0][1]); w2.y = PACKW(D[0][0][2], D[0][0][3]);
  *(uint2*)(Gc + ct * 32 + 4 * g) = w2;
  w2.x = PACKW(D[0][1][0], D[0][1][1]); w2.y = PACKW(D[0][1][2], D[0][1][3]);
  *(uint2*)(Gc + (16 + ct) * 32 + 4 * g) = w2;
  w2.x = PACKW(D[1][0][0], D[1][0][1]); w2.y = PACKW(D[1][0][2], D[1][0][3]);
  *(uint2*)(Gc + ct * 32 + 16 + 4 * g) = w2;
  w2.x = PACKW(D[1][1][0], D[1][1][1]); w2.y = PACKW(D[1][1][2], D[1][1][3]);
  *(uint2*)(Gc + (16 + ct) * 32 + 16 + 4 * g) = w2;
  if (l == 0) Rc[bid] = R;
}

// ============ Kernel 3 (passB): fold 8 chunk matrices + terminal LSE =======
__global__ __launch_bounds__(64) void passB(
    const ushort* __restrict__ eemit, const float* __restrict__ trans,
    const ushort* __restrict__ G, const float* __restrict__ Rc,
    float* __restrict__ out) {
  const int b = blockIdx.x;
  const int j = threadIdx.x;
  const bool act = j < Tn;
  const int jj = act ? j : 0;

  // u0_j = ee_0[j] * exp(trans[j, START])
  float v = act ? bf2f(eemit[(size_t)b * (Ln * Tn) + jj]) *
                      __expf(trans[jj * Tn + START_TAG])
                : 0.f;
  float R = 0.f;
  const ushort* Gb = G + (size_t)b * (NCH * 1024);

#pragma unroll 1
  for (int c = 0; c < NCH; ++c) {
    const ushort* Gc = Gb + c * 1024;
    float p[24];
#pragma unroll
    for (int k = 0; k < 24; ++k) p[k] = bf2f(Gc[k * 32 + jj]);
    float s = 0.f;
#pragma unroll
    for (int k = 0; k < 24; ++k) s = fmaf(p[k], rlf(v, k), s);
    v = act ? s : 0.f;
    R += Rc[b * NCH + c];
    float mx = v;
    mx = fmaxf(mx, __shfl_xor(mx, 1, 64));
    mx = fmaxf(mx, __shfl_xor(mx, 2, 64));
    mx = fmaxf(mx, __shfl_xor(mx, 4, 64));
    mx = fmaxf(mx, __shfl_xor(mx, 8, 64));
    mx = fmaxf(mx, __shfl_xor(mx, 16, 64));
    mx = fmaxf(mx, __shfl_xor(mx, 32, 64));
    int eb = ((__float_as_int(mx) >> 23) & 255) - 127;
    v *= __int_as_float((uint)(127 - eb) << 23);
    R += (float)eb * 0.6931471805599453f;
  }

  float term = act ? v * __expf(trans[STOP_TAG * Tn + jj]) : 0.f;
  term += __shfl_xor(term, 1, 64);
  term += __shfl_xor(term, 2, 64);
  term += __shfl_xor(term, 4, 64);
  term += __shfl_xor(term, 8, 64);
  term += __shfl_xor(term, 16, 64);
  term += __shfl_xor(term, 32, 64);
  if (j == 0) out[b] = R + logf(term);
}

// ============ launch =======================================================
extern "C" void kernel_launch(void* const* d_in, const int* in_sizes, int n_in,
                              void* d_out, int out_size, void* d_ws,
                              size_t ws_size, hipStream_t stream) {
  const float* feat = (const float*)d_in[0];   // [B, L, H]
  const float* W = (const float*)d_in[1];      // [T, H]
  const float* bias = (const float*)d_in[2];   // [T]
  const float* trans = (const float*)d_in[3];  // [T, T]
  const int* lengths = (const int*)d_in[4];    // [B]
  float* out = (float*)d_out;                  // [B]

  ushort* eemit = (ushort*)d_ws;                     // 3,145,728 B
  ushort* Wbf = (ushort*)((char*)d_ws + 3145728);    //    24,576 B
  ushort* G = (ushort*)((char*)d_ws + 3170304);      // 2,097,152 B
  float* Rc = (float*)((char*)d_ws + 5267456);       //     4,096 B

  wconv<<<48, 256, 0, stream>>>(W, Wbf);
  emit_kernel<<<256, 256, 0, stream>>>(feat, Wbf, bias, eemit);
  passA<<<Bn * NCH, 64, 0, stream>>>(eemit, trans, lengths, G, Rc);
  passB<<<Bn, 64, 0, stream>>>(eemit, trans, G, Rc, out);
}

// Round 5
// 224.756 us; speedup vs baseline: 1.8546x; 1.0253x over previous
//
#include <hip/hip_runtime.h>
#include <hip/hip_bf16.h>

typedef unsigned int uint;
typedef unsigned short ushort;

#define Bn 128
#define Ln 512
#define Hn 512
#define Tn 24
#define START_TAG 22
#define STOP_TAG 23
#define NCH 16  // chunks per batch
#define CHL 32  // timesteps per chunk

using frag_ab = __attribute__((ext_vector_type(8))) short;
using frag_cd = __attribute__((ext_vector_type(4))) float;
union ABU { frag_ab f; uint u[4]; };

// pack two f32 into one u32 of 2 bf16 (truncation) via v_perm
#define PACKW(x, y) \
  __builtin_amdgcn_perm(__float_as_uint(y), __float_as_uint(x), 0x07060302u)
#define MFMA16 __builtin_amdgcn_mfma_f32_16x16x32_bf16

__device__ __forceinline__ float bf2f(ushort v) {
  return __uint_as_float(((uint)v) << 16);
}
__device__ __forceinline__ float rlf(float v, int l) {
  return __int_as_float(__builtin_amdgcn_readlane(__float_as_int(v), l));
}
__device__ __forceinline__ float rfl(float v) {
  return __int_as_float(__builtin_amdgcn_readfirstlane(__float_as_int(v)));
}
__device__ __forceinline__ uint bperm(int addr, uint v) {
  return (uint)__builtin_amdgcn_ds_bpermute(addr, (int)v);
}

// ================= Fused kernel: emission GEMM + chunk chain ===============
// Block = (batch b, chunk c of 32 timesteps), 128 threads (2 waves).
// Phase 1 (both waves): ee[lt][tag] = exp(feat·W^T + bias) via MFMA -> LDS f32.
// Phase 2 (one wave): P <- diag(ee_t)·E·P over the chunk, D->B relayout via
// ds_bpermute (no LDS bounce); G[chunk] = P (bf16), Rc = log-scale carried.
__global__ __launch_bounds__(128) void fused_kernel(
    const float* __restrict__ feat, const float* __restrict__ W,
    const float* __restrict__ bias, const float* __restrict__ trans,
    const int* __restrict__ lengths, ushort* __restrict__ G,
    float* __restrict__ Rc, float* __restrict__ u0buf) {
  __shared__ float ee[CHL][28];
  const int bid = blockIdx.x;
  const int b = bid >> 4, c = bid & 15;
  const int wv = threadIdx.x >> 6, l = threadIdx.x & 63;
  const int ct = l & 15, g = l >> 4;
  const int ct2 = 16 + (ct & 7);

  // ---------------- phase 1: emission GEMM (both waves) ----------------
  const float* fp = feat + (size_t)(bid * CHL + wv * 16 + ct) * Hn + 8 * g;
  const float* wp0 = W + ct * Hn + 8 * g;
  const float* wp1 = W + ct2 * Hn + 8 * g;
  frag_cd acc0 = {0.f, 0.f, 0.f, 0.f}, acc1 = {0.f, 0.f, 0.f, 0.f};
#pragma unroll 2
  for (int kk = 0; kk < 16; ++kk) {
    const int off = kk * 32;
    float4 fa = *(const float4*)(fp + off);
    float4 fb = *(const float4*)(fp + off + 4);
    float4 wa0 = *(const float4*)(wp0 + off);
    float4 wb0 = *(const float4*)(wp0 + off + 4);
    float4 wa1 = *(const float4*)(wp1 + off);
    float4 wb1 = *(const float4*)(wp1 + off + 4);
    ABU A, B0, B1;
    A.u[0] = PACKW(fa.x, fa.y);  A.u[1] = PACKW(fa.z, fa.w);
    A.u[2] = PACKW(fb.x, fb.y);  A.u[3] = PACKW(fb.z, fb.w);
    B0.u[0] = PACKW(wa0.x, wa0.y); B0.u[1] = PACKW(wa0.z, wa0.w);
    B0.u[2] = PACKW(wb0.x, wb0.y); B0.u[3] = PACKW(wb0.z, wb0.w);
    B1.u[0] = PACKW(wa1.x, wa1.y); B1.u[1] = PACKW(wa1.z, wa1.w);
    B1.u[2] = PACKW(wb1.x, wb1.y); B1.u[3] = PACKW(wb1.z, wb1.w);
    acc0 = MFMA16(A.f, B0.f, acc0, 0, 0, 0);
    acc1 = MFMA16(A.f, B1.f, acc1, 0, 0, 0);
  }
  const float bs0 = bias[ct];
  const float bs1 = bias[ct2];
  const int rr = wv * 16 + 4 * g;
#pragma unroll
  for (int r = 0; r < 4; ++r) {
    ee[rr + r][ct] = __expf(acc0[r] + bs0);
    if (ct < 8) ee[rr + r][16 + ct] = __expf(acc1[r] + bs1);
  }
  __syncthreads();
  if (c == 0 && threadIdx.x < Tn)
    u0buf[b * Tn + threadIdx.x] = ee[0][threadIdx.x];

  // ---------------- phase 2: chunk chain (one wave) ----------------
  const int cw = (bid >> 8) & 1;  // spread chain waves across SIMDs
  if (wv != cw) return;

  const int len = lengths[b];
  const int lo = (c == 0) ? 1 : 0;
  int hi = len - c * CHL;
  if (hi > CHL) hi = CHL;

  // E rows for this lane's A-frag slots (rows ct and ct2; zero-pad >= 24)
  float E0[8], E1[8];
#pragma unroll
  for (int i = 0; i < 8; ++i) {
    int k = 8 * g + i;
    int kc = k < 23 ? k : 23;
    E0[i] = (k < Tn) ? __expf(trans[ct * Tn + kc]) : 0.f;
    E1[i] = (k < Tn && ct < 8) ? __expf(trans[ct2 * Tn + kc]) : 0.f;
  }

  // P = I (32x32) in D-frag form: quadrant (m,n), value at row 16m+4g+r,
  // col 16n+ct.  D00/D11 diagonal, D01/D10 zero.
  frag_cd D00, D01, D10, D11;
#pragma unroll
  for (int r = 0; r < 4; ++r) {
    float dv = (4 * g + r == ct) ? 1.f : 0.f;
    D00[r] = dv; D11[r] = dv; D01[r] = 0.f; D10[r] = 0.f;
  }

  float R = 0.f;
  const int addr0 = (ct + 32 * (g & 1)) * 4;  // src lane ct+16*(2(g&1))
  const int addr1 = addr0 + 64;               // src lane ct+16*(2(g&1)+1)
  const bool mhi = (g >= 2);

#define RENORMF()                                                       \
  do {                                                                  \
    float ref = fmaxf(fmaxf(D00[0], D00[1]), fmaxf(D00[2], D00[3]));    \
    ref = rfl(ref);                                                     \
    int ebx = ((__float_as_int(ref) >> 23) & 255) - 127;                \
    float sc = __int_as_float((uint)(127 - ebx) << 23);                 \
    _Pragma("unroll") for (int r = 0; r < 4; ++r) {                     \
      D00[r] *= sc; D01[r] *= sc; D10[r] *= sc; D11[r] *= sc;           \
    }                                                                   \
    R += (float)ebx * 0.6931471805599453f;                              \
  } while (0)

  int stepc = 0;
  for (int lt = lo; lt < hi; ++lt) {
    float ea = ee[lt][ct];
    float eb = ee[lt][ct2];
    // pack current P quadrants to bf16 pairs (elems {0,1} and {2,3})
    uint p000 = PACKW(D00[0], D00[1]), p001 = PACKW(D00[2], D00[3]);
    uint p010 = PACKW(D01[0], D01[1]), p011 = PACKW(D01[2], D01[3]);
    uint p100 = PACKW(D10[0], D10[1]), p101 = PACKW(D10[2], D10[3]);
    uint p110 = PACKW(D11[0], D11[1]), p111 = PACKW(D11[2], D11[3]);
    // redistribute D -> B-frags: lane(ct,g) needs P[k=8g+i][col] bf16
    ABU Bf0, Bf1;
    {
      uint a0 = bperm(addr0, p000), b0 = bperm(addr0, p100);
      uint a1 = bperm(addr0, p001), b1 = bperm(addr0, p101);
      uint a2 = bperm(addr1, p000), b2 = bperm(addr1, p100);
      uint a3 = bperm(addr1, p001), b3 = bperm(addr1, p101);
      Bf0.u[0] = mhi ? b0 : a0;
      Bf0.u[1] = mhi ? b1 : a1;
      Bf0.u[2] = mhi ? b2 : a2;
      Bf0.u[3] = mhi ? b3 : a3;
      a0 = bperm(addr0, p010); b0 = bperm(addr0, p110);
      a1 = bperm(addr0, p011); b1 = bperm(addr0, p111);
      a2 = bperm(addr1, p010); b2 = bperm(addr1, p110);
      a3 = bperm(addr1, p011); b3 = bperm(addr1, p111);
      Bf1.u[0] = mhi ? b0 : a0;
      Bf1.u[1] = mhi ? b1 : a1;
      Bf1.u[2] = mhi ? b2 : a2;
      Bf1.u[3] = mhi ? b3 : a3;
    }
    // A = diag(ee)*E rows (ct and ct2)
    ABU A0, A1;
    A0.u[0] = PACKW(ea * E0[0], ea * E0[1]);
    A0.u[1] = PACKW(ea * E0[2], ea * E0[3]);
    A0.u[2] = PACKW(ea * E0[4], ea * E0[5]);
    A0.u[3] = PACKW(ea * E0[6], ea * E0[7]);
    A1.u[0] = PACKW(eb * E1[0], eb * E1[1]);
    A1.u[1] = PACKW(eb * E1[2], eb * E1[3]);
    A1.u[2] = PACKW(eb * E1[4], eb * E1[5]);
    A1.u[3] = PACKW(eb * E1[6], eb * E1[7]);
    frag_cd z = {0.f, 0.f, 0.f, 0.f};
    D00 = MFMA16(A0.f, Bf0.f, z, 0, 0, 0);
    D01 = MFMA16(A0.f, Bf1.f, z, 0, 0, 0);
    D10 = MFMA16(A1.f, Bf0.f, z, 0, 0, 0);
    D11 = MFMA16(A1.f, Bf1.f, z, 0, 0, 0);
    if ((++stepc & 3) == 0) RENORMF();
  }
  RENORMF();  // bound G entries before bf16 store (no-op if already done)

  // store chunk product column-major bf16: Gc[col*32 + row]
  ushort* Gc = G + (size_t)bid * 1024;
  uint2 w2;
  w2.x = PACKW(D00[0], D00[1]); w2.y = PACKW(D00[2], D00[3]);
  *(uint2*)(Gc + ct * 32 + 4 * g) = w2;
  w2.x = PACKW(D01[0], D01[1]); w2.y = PACKW(D01[2], D01[3]);
  *(uint2*)(Gc + (16 + ct) * 32 + 4 * g) = w2;
  w2.x = PACKW(D10[0], D10[1]); w2.y = PACKW(D10[2], D10[3]);
  *(uint2*)(Gc + ct * 32 + 16 + 4 * g) = w2;
  w2.x = PACKW(D11[0], D11[1]); w2.y = PACKW(D11[2], D11[3]);
  *(uint2*)(Gc + (16 + ct) * 32 + 16 + 4 * g) = w2;
  if (l == 0) Rc[bid] = R;
}

// ================= passB: fold 16 chunk matrices + terminal LSE ============
__global__ __launch_bounds__(64) void passB(
    const float* __restrict__ trans, const ushort* __restrict__ G,
    const float* __restrict__ Rc, const float* __restrict__ u0buf,
    float* __restrict__ out) {
  const int b = blockIdx.x;
  const int j = threadIdx.x;
  const bool act = j < Tn;
  const int jj = act ? j : 0;

  float v = act ? u0buf[b * Tn + jj] * __expf(trans[jj * Tn + START_TAG]) : 0.f;
  float R = 0.f;
  const ushort* Gb = G + (size_t)b * (NCH * 1024);

#pragma unroll 1
  for (int c = 0; c < NCH; ++c) {
    const ushort* Gc = Gb + c * 1024;
    float p[24];
#pragma unroll
    for (int k = 0; k < 24; ++k) p[k] = bf2f(Gc[k * 32 + jj]);
    float s = 0.f;
#pragma unroll
    for (int k = 0; k < 24; ++k) s = fmaf(p[k], rlf(v, k), s);
    v = act ? s : 0.f;
    R += Rc[b * NCH + c];
    float ref = rfl(v);  // lane 0 = tag 0, generic nonzero
    int ebx = ((__float_as_int(ref) >> 23) & 255) - 127;
    v *= __int_as_float((uint)(127 - ebx) << 23);
    R += (float)ebx * 0.6931471805599453f;
  }

  float term = act ? v * __expf(trans[STOP_TAG * Tn + jj]) : 0.f;
  term += __shfl_xor(term, 1, 64);
  term += __shfl_xor(term, 2, 64);
  term += __shfl_xor(term, 4, 64);
  term += __shfl_xor(term, 8, 64);
  term += __shfl_xor(term, 16, 64);
  term += __shfl_xor(term, 32, 64);
  if (j == 0) out[b] = R + logf(term);
}

// ================= launch ==================================================
extern "C" void kernel_launch(void* const* d_in, const int* in_sizes, int n_in,
                              void* d_out, int out_size, void* d_ws,
                              size_t ws_size, hipStream_t stream) {
  const float* feat = (const float*)d_in[0];   // [B, L, H]
  const float* W = (const float*)d_in[1];      // [T, H]
  const float* bias = (const float*)d_in[2];   // [T]
  const float* trans = (const float*)d_in[3];  // [T, T]
  const int* lengths = (const int*)d_in[4];    // [B]
  float* out = (float*)d_out;                  // [B]

  ushort* G = (ushort*)d_ws;                        // 4,194,304 B
  float* Rc = (float*)((char*)d_ws + 4194304);      //     8,192 B
  float* u0buf = (float*)((char*)d_ws + 4202496);   //    12,288 B

  fused_kernel<<<Bn * NCH, 128, 0, stream>>>(feat, W, bias, trans, lengths, G,
                                             Rc, u0buf);
  passB<<<Bn, 64, 0, stream>>>(trans, G, Rc, u0buf, out);
}